// Round 2
// baseline (237.683 us; speedup 1.0000x reference)
//
#include <hip/hip_runtime.h>
#include <math.h>

#define NTGT 512
#define NA 3
#define NCLS 80
#define EPL 7680            // entries per level = 5*3*512
#define NE  23040           // total entries = 3*EPL
#define CLS_TOT 1843200     // NE*80
#define CLS_PER_LVL 614400  // EPL*80

__device__ __constant__ float c_anch[3][3][2] = {
  {{10.f,13.f},{16.f,30.f},{33.f,23.f}},
  {{30.f,61.f},{62.f,45.f},{59.f,119.f}},
  {{116.f,90.f},{156.f,198.f},{373.f,326.f}},
};

struct alignas(16) Rec {
  long long off;   // element offset of (im,a,gy,gx) cell in the level tensor
  int ci;          // class id
  int valid;
};

__device__ inline float sigm(float x){ return 1.0f/(1.0f+expf(-x)); }
__device__ inline float bcel(float x, float z){
  return fmaxf(x,0.0f) - x*z + log1pf(expf(-fabsf(x)));
}
__device__ inline double wred(double v){
  #pragma unroll
  for(int o=32;o;o>>=1) v += __shfl_down(v,o);
  return v;
}

// Phase 1: one thread per entry. 5 channel loads, giou, box/obj/cnt sums,
// and writes the Rec consumed by k_cls.
// acc: [l*4+0]=box, [l*4+1]=cls, [l*4+2]=cnt, [l*4+3]=obj corr, [12]=softplus.
__global__ __launch_bounds__(256)
void k_entry(const float* __restrict__ p0, const float* __restrict__ p1,
             const float* __restrict__ p2, const float* __restrict__ tg,
             double* __restrict__ acc, Rec* __restrict__ recs)
{
  const int e   = blockIdx.x*256 + threadIdx.x;    // < 23040 exactly
  const int lvl = e / EPL;
  const int r   = e % EPL;
  const int c   = r / (NA*NTGT);
  const int a   = (r / NTGT) % NA;
  const int n   = r % NTGT;
  const int W   = 80 >> lvl;                       // H == W at every level
  const float* __restrict__ p = (lvl==0) ? p0 : (lvl==1) ? p1 : p2;

  const float t0 = tg[n*6+0];
  const float t1 = tg[n*6+1];
  const float tx = tg[n*6+2]*(float)W;
  const float ty = tg[n*6+3]*(float)W;
  const float tw = tg[n*6+4]*(float)W;
  const float th = tg[n*6+5]*(float)W;

  const float aw = c_anch[lvl][a][0], ah = c_anch[lvl][a][1];
  const float rw = tw/aw, rh = th/ah;
  const float mr = fmaxf(fmaxf(rw, 1.0f/rw), fmaxf(rh, 1.0f/rh));
  const bool sel = mr < 4.0f;

  const float fx = tx - floorf(tx);
  const float fy = ty - floorf(ty);
  float ox = 0.f, oy = 0.f; bool cond = true;
  if (c==1){ cond = (fx<0.5f) && (tx>1.0f);               ox =  0.5f; }
  else if (c==2){ cond = (fy<0.5f) && (ty>1.0f);          oy =  0.5f; }
  else if (c==3){ cond = (fx>0.5f) && (tx<(float)W-1.0f); ox = -0.5f; }
  else if (c==4){ cond = (fy>0.5f) && (ty<(float)W-1.0f); oy = -0.5f; }

  const bool valid = sel && cond;
  double vbox=0.0, vcnt=0.0, vobj=0.0;
  long long off = 0;
  if (valid){
    const int gridx = (int)(tx - ox);
    const int gridy = (int)(ty - oy);
    const float gxx = tx - (float)gridx;
    const float gyy = ty - (float)gridy;
    const int gx = min(max(gridx,0), W-1);
    const int gy = min(max(gridy,0), W-1);
    const int im = (int)t0;
    const long long HW = (long long)W*W;
    off = ((long long)(im*255 + a*85)*W + gy)*W + gx;
    const float* base = p + off;

    const float o0=base[0], o1=base[HW], o2=base[2*HW], o3=base[3*HW], o4=base[4*HW];
    const float px = sigm(o0)*2.f - 0.5f;
    const float py = sigm(o1)*2.f - 0.5f;
    const float s2 = sigm(o2)*2.f; const float pw = s2*s2*aw;
    const float s3 = sigm(o3)*2.f; const float ph = s3*s3*ah;

    const float ax0=px-pw/2.f, ax1=px+pw/2.f, ay0=py-ph/2.f, ay1=py+ph/2.f;
    const float bx0=gxx-tw/2.f, bx1=gxx+tw/2.f, by0=gyy-th/2.f, by1=gyy+th/2.f;
    const float iw = fmaxf(fminf(ax1,bx1)-fmaxf(ax0,bx0), 0.f);
    const float ih = fmaxf(fminf(ay1,by1)-fmaxf(ay0,by0), 0.f);
    const float inter = iw*ih;
    const float uni = (ax1-ax0)*(ay1-ay0) + (bx1-bx0)*(by1-by0) - inter;
    const float iou = inter/uni;
    const float cwid = fmaxf(ax1,bx1)-fminf(ax0,bx0)+1e-16f;
    const float chei = fmaxf(ay1,by1)-fminf(ay0,by0);
    const float ca = cwid*chei + 1e-16f;
    const float g = iou - (ca-uni)/ca;

    vbox = (double)(1.0f - g);
    vcnt = 1.0;
    vobj = -(double)o4 * (double)fmaxf(g, 0.f);   // bce(x,g)-bce(x,0) = -x*g
  }

  Rec rec; rec.off = off; rec.ci = (int)t1; rec.valid = valid ? 1 : 0;
  recs[e] = rec;

  // lvl is wave-uniform (EPL % 64 == 0)
  vbox = wred(vbox); vcnt = wred(vcnt); vobj = wred(vobj);
  if ((threadIdx.x & 63) == 0){
    atomicAdd(&acc[lvl*4+0], vbox);
    atomicAdd(&acc[lvl*4+2], vcnt);
    atomicAdd(&acc[lvl*4+3], vobj);
  }
}

// Phase 2: one thread per (entry, class channel). One scattered load each.
__global__ __launch_bounds__(256)
void k_cls(const float* __restrict__ p0, const float* __restrict__ p1,
           const float* __restrict__ p2, const Rec* __restrict__ recs,
           double* __restrict__ acc)
{
  const int i   = blockIdx.x*256 + threadIdx.x;    // < 1843200 exactly
  const int lvl = i / CLS_PER_LVL;
  const int r   = i % CLS_PER_LVL;
  const int e   = r / NCLS;
  const int k   = r % NCLS;

  const Rec rec = recs[lvl*EPL + e];
  double v = 0.0;
  if (rec.valid){
    const float* __restrict__ p = (lvl==0) ? p0 : (lvl==1) ? p1 : p2;
    const int W = 80 >> lvl;
    const long long HW = (long long)W*W;
    const float x = p[rec.off + (long long)(5+k)*HW];
    v = (double)bcel(x, (k==rec.ci) ? 1.0f : 0.0f);
  }

  v = wred(v);
  __shared__ double sh[4];
  if ((threadIdx.x & 63) == 0) sh[threadIdx.x>>6] = v;
  __syncthreads();
  if (threadIdx.x == 0){
    // lvl is block-uniform (CLS_PER_LVL % 256 == 0)
    atomicAdd(&acc[lvl*4+1], sh[0]+sh[1]+sh[2]+sh[3]);
  }
}

// Weighted softplus over the objectness channels (bce(x,0) part of obj loss).
__global__ __launch_bounds__(256)
void k_obj(const float* __restrict__ p0, const float* __restrict__ p1,
           const float* __restrict__ p2, double* __restrict__ acc)
{
  const int TOT = 403200;   // 307200 + 76800 + 19200
  double s = 0.0;
  for (int i = blockIdx.x*blockDim.x + threadIdx.x; i < TOT;
       i += gridDim.x*blockDim.x){
    float x; double w;
    if (i < 307200){
      const int b=i/19200, r=i%19200, a=r/6400, pos=r%6400;
      x = p0[((long)(b*255 + a*85 + 4))*6400 + pos];
      w = 4.0/307200.0;
    } else if (i < 384000){
      const int j=i-307200;
      const int b=j/4800, r=j%4800, a=r/1600, pos=r%1600;
      x = p1[((long)(b*255 + a*85 + 4))*1600 + pos];
      w = 1.0/76800.0;
    } else {
      const int j=i-384000;
      const int b=j/1200, r=j%1200, a=r/400, pos=r%400;
      x = p2[((long)(b*255 + a*85 + 4))*400 + pos];
      w = 0.4/19200.0;
    }
    const float sp = fmaxf(x,0.f) + log1pf(expf(-fabsf(x)));
    s += w * (double)sp;
  }
  s = wred(s);
  __shared__ double sh[4];
  if ((threadIdx.x & 63) == 0) sh[threadIdx.x>>6] = s;
  __syncthreads();
  if (threadIdx.x == 0){
    atomicAdd(&acc[12], sh[0]+sh[1]+sh[2]+sh[3]);
  }
}

__global__ void k_final(const double* __restrict__ acc, float* __restrict__ out)
{
  double lbox = 0.0, lcls = 0.0;
  double lobj = acc[12];
  const double bal[3] = {4.0, 1.0, 0.4};
  const double sz[3]  = {307200.0, 76800.0, 19200.0};
  for (int l=0; l<3; l++){
    const double cnt = acc[l*4+2];
    const double den = cnt > 1.0 ? cnt : 1.0;
    if (cnt > 0.0){
      lbox += acc[l*4+0] / den;
      lcls += acc[l*4+1] / (den * 80.0);
    }
    lobj += bal[l] * acc[l*4+3] / sz[l];
  }
  const double loss = (0.05*lbox + 1.0*lobj + 0.5*lcls) * 16.0;
  out[0] = (float)loss;
}

extern "C" void kernel_launch(void* const* d_in, const int* in_sizes, int n_in,
                              void* d_out, int out_size, void* d_ws, size_t ws_size,
                              hipStream_t stream)
{
  const float* p0 = (const float*)d_in[0];
  const float* p1 = (const float*)d_in[1];
  const float* p2 = (const float*)d_in[2];
  const float* tg = (const float*)d_in[3];
  double* acc = (double*)d_ws;
  Rec* recs = (Rec*)((char*)d_ws + 256);

  hipMemsetAsync(d_ws, 0, 16*sizeof(double), stream);
  k_entry<<<NE/256, 256, 0, stream>>>(p0, p1, p2, tg, acc, recs);
  k_cls<<<CLS_TOT/256, 256, 0, stream>>>(p0, p1, p2, recs, acc);
  k_obj<<<420, 256, 0, stream>>>(p0, p1, p2, acc);
  k_final<<<1,1,0,stream>>>(acc, (float*)d_out);
}

// Round 3
// 176.950 us; speedup vs baseline: 1.3432x; 1.3432x over previous
//
#include <hip/hip_runtime.h>
#include <math.h>

#define NTGT 512
#define NA 3
#define NCLS 80
#define EPL 7680              // entries per level = 5*3*512
#define NE  23040             // 3*EPL
#define OBJ_TOT 403200        // 307200 + 76800 + 19200
#define OBJ_BLOCKS 1575       // 403200/256
#define ENT_BLOCKS 1440       // 23040*16/256
#define NBLK 3015             // OBJ_BLOCKS + ENT_BLOCKS
#define PSTRIDE 3072          // padded NBLK for partials layout part[q*PSTRIDE+b]

__device__ __constant__ float c_anch[3][3][2] = {
  {{10.f,13.f},{16.f,30.f},{33.f,23.f}},
  {{30.f,61.f},{62.f,45.f},{59.f,119.f}},
  {{116.f,90.f},{156.f,198.f},{373.f,326.f}},
};

__device__ inline float sigm(float x){ return 1.0f/(1.0f+expf(-x)); }
__device__ inline float bcel(float x, float z){
  return fmaxf(x,0.0f) - x*z + log1pf(expf(-fabsf(x)));
}
__device__ inline double wred(double v){
  #pragma unroll
  for(int o=32;o;o>>=1) v += __shfl_down(v,o);
  return v;
}
// Block reduce (256 threads = 4 waves). All threads must call. Result valid in all threads.
__device__ inline double bred(double v, double* sh){
  v = wred(v);
  __syncthreads();
  if ((threadIdx.x & 63) == 0) sh[threadIdx.x>>6] = v;
  __syncthreads();
  return sh[0]+sh[1]+sh[2]+sh[3];
}

// Fused kernel. Partials: part[q*PSTRIDE + blockIdx.x], q in [0,13):
//   q = lvl*4 + {0:box,1:cls,2:cnt,3:obj_corr}; q=12: weighted softplus.
// Every block writes ALL 13 of its slots (ws is poisoned each run).
__global__ __launch_bounds__(256)
void k_main(const float* __restrict__ p0, const float* __restrict__ p1,
            const float* __restrict__ p2, const float* __restrict__ tg,
            double* __restrict__ part)
{
  __shared__ double sh[4];
  double out[13];
  #pragma unroll
  for (int q=0;q<13;q++) out[q]=0.0;

  if (blockIdx.x < OBJ_BLOCKS){
    // ---- objectness softplus domain (coalesced within each (b,a) plane) ----
    const int i = blockIdx.x*256 + threadIdx.x;   // < 403200 exactly
    float x; double w;
    if (i < 307200){
      const int b=i/19200, r=i%19200, a=r/6400, pos=r%6400;
      x = p0[((long)(b*255 + a*85 + 4))*6400 + pos];
      w = 4.0/307200.0;
    } else if (i < 384000){
      const int j=i-307200;
      const int b=j/4800, r=j%4800, a=r/1600, pos=r%1600;
      x = p1[((long)(b*255 + a*85 + 4))*1600 + pos];
      w = 1.0/76800.0;
    } else {
      const int j=i-384000;
      const int b=j/1200, r=j%1200, a=r/400, pos=r%400;
      x = p2[((long)(b*255 + a*85 + 4))*400 + pos];
      w = 0.4/19200.0;
    }
    const float sp = fmaxf(x,0.f) + log1pf(expf(-fabsf(x)));
    out[12] = bred(w*(double)sp, sh);
  } else {
    // ---- entry domain: 16 threads per entry ----
    const int te  = (blockIdx.x - OBJ_BLOCKS)*256 + threadIdx.x;  // < 368640
    const int e   = te >> 4;
    const int sub = te & 15;
    const int lvl = e / EPL;          // block-uniform (7680*16 % 256 == 0)
    const int r   = e % EPL;
    const int c   = r / (NA*NTGT);
    const int a   = (r / NTGT) % NA;
    const int n   = r % NTGT;
    const int W   = 80 >> lvl;
    const float* __restrict__ p = (lvl==0) ? p0 : (lvl==1) ? p1 : p2;

    const float t0 = tg[n*6+0];
    const float t1 = tg[n*6+1];
    const float tx = tg[n*6+2]*(float)W;
    const float ty = tg[n*6+3]*(float)W;
    const float tw = tg[n*6+4]*(float)W;
    const float th = tg[n*6+5]*(float)W;

    const float aw = c_anch[lvl][a][0], ah = c_anch[lvl][a][1];
    const float rw = tw/aw, rh = th/ah;
    const float mr = fmaxf(fmaxf(rw, 1.0f/rw), fmaxf(rh, 1.0f/rh));
    const bool sel = mr < 4.0f;

    const float fx = tx - floorf(tx);
    const float fy = ty - floorf(ty);
    float ox = 0.f, oy = 0.f; bool cond = true;
    if (c==1){ cond = (fx<0.5f) && (tx>1.0f);               ox =  0.5f; }
    else if (c==2){ cond = (fy<0.5f) && (ty>1.0f);          oy =  0.5f; }
    else if (c==3){ cond = (fx>0.5f) && (tx<(float)W-1.0f); ox = -0.5f; }
    else if (c==4){ cond = (fy>0.5f) && (ty<(float)W-1.0f); oy = -0.5f; }
    const bool valid = sel && cond;

    double vbox=0.0, vcnt=0.0, vobj=0.0, vcls=0.0;
    if (valid){
      const int gridx = (int)(tx - ox);
      const int gridy = (int)(ty - oy);
      const int gx = min(max(gridx,0), W-1);
      const int gy = min(max(gridy,0), W-1);
      const int im = (int)t0;
      const int ci = (int)t1;
      const long long HW = (long long)W*W;
      const long long off = ((long long)(im*255 + a*85)*W + gy)*W + gx;
      const float* base = p + off;

      // class BCE: 5 channels per sub-thread
      float cs = 0.f;
      #pragma unroll
      for (int j=0;j<5;j++){
        const int k = sub*5 + j;
        const float x = base[(long long)(5+k)*HW];
        cs += bcel(x, (k==ci) ? 1.0f : 0.0f);
      }
      vcls = (double)cs;

      if (sub == 0){
        const float gxx = tx - (float)gridx;
        const float gyy = ty - (float)gridy;
        const float o0=base[0], o1=base[HW], o2=base[2*HW], o3=base[3*HW], o4=base[4*HW];
        const float px = sigm(o0)*2.f - 0.5f;
        const float py = sigm(o1)*2.f - 0.5f;
        const float s2 = sigm(o2)*2.f; const float pw = s2*s2*aw;
        const float s3 = sigm(o3)*2.f; const float ph = s3*s3*ah;

        const float ax0=px-pw/2.f, ax1=px+pw/2.f, ay0=py-ph/2.f, ay1=py+ph/2.f;
        const float bx0=gxx-tw/2.f, bx1=gxx+tw/2.f, by0=gyy-th/2.f, by1=gyy+th/2.f;
        const float iw = fmaxf(fminf(ax1,bx1)-fmaxf(ax0,bx0), 0.f);
        const float ih = fmaxf(fminf(ay1,by1)-fmaxf(ay0,by0), 0.f);
        const float inter = iw*ih;
        const float uni = (ax1-ax0)*(ay1-ay0) + (bx1-bx0)*(by1-by0) - inter;
        const float iou = inter/uni;
        const float cwid = fmaxf(ax1,bx1)-fminf(ax0,bx0)+1e-16f;
        const float chei = fmaxf(ay1,by1)-fminf(ay0,by0);
        const float ca = cwid*chei + 1e-16f;
        const float g = iou - (ca-uni)/ca;

        vbox = (double)(1.0f - g);
        vcnt = 1.0;
        vobj = -(double)o4 * (double)fmaxf(g, 0.f);  // bce(x,g)-bce(x,0) = -x*g
      }
    }

    out[lvl*4+0] = bred(vbox, sh);
    out[lvl*4+1] = bred(vcls, sh);
    out[lvl*4+2] = bred(vcnt, sh);
    out[lvl*4+3] = bred(vobj, sh);
  }

  if (threadIdx.x == 0){
    #pragma unroll
    for (int q=0;q<13;q++) part[q*PSTRIDE + blockIdx.x] = out[q];
  }
}

__global__ __launch_bounds__(256)
void k_final(const double* __restrict__ part, float* __restrict__ out)
{
  __shared__ double sh[4];
  double s[13];
  #pragma unroll
  for (int q=0;q<13;q++) s[q]=0.0;
  for (int b = threadIdx.x; b < NBLK; b += 256){
    #pragma unroll
    for (int q=0;q<13;q++) s[q] += part[q*PSTRIDE + b];
  }
  double S[13];
  #pragma unroll
  for (int q=0;q<13;q++) S[q] = bred(s[q], sh);

  if (threadIdx.x == 0){
    double lbox = 0.0, lcls = 0.0;
    double lobj = S[12];
    const double bal[3] = {4.0, 1.0, 0.4};
    const double sz[3]  = {307200.0, 76800.0, 19200.0};
    for (int l=0; l<3; l++){
      const double cnt = S[l*4+2];
      const double den = cnt > 1.0 ? cnt : 1.0;
      if (cnt > 0.0){
        lbox += S[l*4+0] / den;
        lcls += S[l*4+1] / (den * 80.0);
      }
      lobj += bal[l] * S[l*4+3] / sz[l];
    }
    const double loss = (0.05*lbox + 1.0*lobj + 0.5*lcls) * 16.0;
    out[0] = (float)loss;
  }
}

extern "C" void kernel_launch(void* const* d_in, const int* in_sizes, int n_in,
                              void* d_out, int out_size, void* d_ws, size_t ws_size,
                              hipStream_t stream)
{
  const float* p0 = (const float*)d_in[0];
  const float* p1 = (const float*)d_in[1];
  const float* p2 = (const float*)d_in[2];
  const float* tg = (const float*)d_in[3];
  double* part = (double*)d_ws;

  k_main<<<NBLK, 256, 0, stream>>>(p0, p1, p2, tg, part);
  k_final<<<1, 256, 0, stream>>>(part, (float*)d_out);
}